// Round 1
// baseline (788.157 us; speedup 1.0000x reference)
//
#include <hip/hip_runtime.h>

#define NN 20000   // nodes
#define EE 640000  // edges
#define CAP 2048   // LDS edge-cache (int2) = 16 KB -> no occupancy throttle
#define WTP 200    // padded k-stride of transposed weight (breaks bank conflict)

typedef __attribute__((ext_vector_type(8))) short short8;
typedef __attribute__((ext_vector_type(4))) float float4v;
typedef __attribute__((ext_vector_type(2))) float float2v;

__device__ __forceinline__ unsigned bf16rn(float x) {
    unsigned u = __float_as_uint(x);
    return (u + 0x7FFFu + ((u >> 16) & 1u)) >> 16;
}
__device__ __forceinline__ unsigned pack2(float a, float b) {
    return bf16rn(a) | (bf16rn(b) << 16);
}
__device__ __forceinline__ float bflo(unsigned u) { return __uint_as_float(u << 16); }
__device__ __forceinline__ float bfhi(unsigned u) { return __uint_as_float(u & 0xFFFF0000u); }

__global__ void build_rowptr_k(const int* __restrict__ rows, int* __restrict__ rp) {
    int r = blockIdx.x * blockDim.x + threadIdx.x;
    if (r > NN) return;
    int lo = 0, hi = EE;
    while (lo < hi) {
        int mid = (lo + hi) >> 1;
        if (rows[mid] < r) lo = mid + 1; else hi = mid;
    }
    rp[r] = lo;
}

// inputs[b][n][f] fp32 -> xb[n][b*64+f] bf16 (node-major, matches y1/y2)
__global__ __launch_bounds__(256) void castxb_k(const float* __restrict__ inp,
                                                unsigned* __restrict__ xb) {
    int n = blockIdx.x, t = threadIdx.x;
    int b = t >> 4, f4 = (t & 15) << 2;
    float4 v = *(const float4*)(inp + ((size_t)b * NN + n) * 64 + f4);
    uint2 o; o.x = pack2(v.x, v.y); o.y = pack2(v.z, v.w);
    *(uint2*)(xb + (size_t)n * 512 + b * 32 + (f4 >> 1)) = o;
}

// Wt[o][k'] bf16, k' = m*64+f, Chebyshev fold: m0: W0-W2, m1: W1, m2: 2*W2
__global__ void wtprep_k(const float* __restrict__ W, unsigned short* __restrict__ wt) {
    int i = blockIdx.x * 256 + threadIdx.x;
    if (i >= 64 * 192) return;
    int o = i / 192, kp = i - o * 192;
    int m = kp >> 6, f = kp & 63;
    float w = W[(f * 3 + m) * 64 + o];
    if (m == 0) w -= W[(f * 3 + 2) * 64 + o];
    else if (m == 2) w += w;
    wt[o * WTP + kp] = (unsigned short)bf16rn(w);
}

__device__ __forceinline__ void accum(const uint4& q, int vbits,
                                      float2v& ac0, float2v& ac1,
                                      float2v& ac2, float2v& ac3) {
    float v_ = __int_as_float(vbits);
    float2v vv = {v_, v_};
    float2v p0 = {bflo(q.x), bfhi(q.x)};
    float2v p1 = {bflo(q.y), bfhi(q.y)};
    float2v p2 = {bflo(q.z), bfhi(q.z)};
    float2v p3 = {bflo(q.w), bfhi(q.w)};
    ac0 = __builtin_elementwise_fma(vv, p0, ac0);
    ac1 = __builtin_elementwise_fma(vv, p1, ac1);
    ac2 = __builtin_elementwise_fma(vv, p2, ac2);
    ac3 = __builtin_elementwise_fma(vv, p3, ac3);
}

// dst[n][c] = sum_e v * src[col][c], bf16 in/out.
// 1D grid of 10000 blocks, XCD-pinned slices: slice = (bid&7) + 8*((bid>>3)/625)
// so each XCD's 4MB L2 holds exactly one 2.56MB channel-slice at a time.
// Gathers use SGPR-base + 32-bit voffset (saddr form, 1 VALU per address) and a
// 2-stage software pipeline with 8 loads in flight per wave.
#define LD4(Q0, Q1, Q2, Q3, V0, V1, V2, V3, IDX)                                  \
    do {                                                                          \
        int2 c0_ = lcv[(IDX)], c1_ = lcv[(IDX) + 1];                              \
        int2 c2_ = lcv[(IDX) + 2], c3_ = lcv[(IDX) + 3];                          \
        V0 = c0_.y; V1 = c1_.y; V2 = c2_.y; V3 = c3_.y;                           \
        Q0 = *(const uint4*)(sb + (size_t)(((unsigned)c0_.x << 11) + tOff));      \
        Q1 = *(const uint4*)(sb + (size_t)(((unsigned)c1_.x << 11) + tOff));      \
        Q2 = *(const uint4*)(sb + (size_t)(((unsigned)c2_.x << 11) + tOff));      \
        Q3 = *(const uint4*)(sb + (size_t)(((unsigned)c3_.x << 11) + tOff));      \
    } while (0)

#define ACC4(Q0, Q1, Q2, Q3, V0, V1, V2, V3)                                      \
    do {                                                                          \
        accum(Q0, V0, ac0, ac1, ac2, ac3);                                        \
        accum(Q1, V1, ac0, ac1, ac2, ac3);                                        \
        accum(Q2, V2, ac0, ac1, ac2, ac3);                                        \
        accum(Q3, V3, ac0, ac1, ac2, ac3);                                        \
    } while (0)

__global__ __launch_bounds__(256, 7) void spmm_bf16_k(
    const unsigned* __restrict__ src, const int* __restrict__ cols,
    const float* __restrict__ vals, const int* __restrict__ rp,
    unsigned* __restrict__ dst) {
    __shared__ int2 lcv[CAP];
    int bid = blockIdx.x;
    int xcd = bid & 7, j = bid >> 3;
    int chunk = j % 625;
    int s = xcd + ((j / 625) << 3);
    int t = threadIdx.x;
    int n0 = chunk * 32;
    int eBase = rp[n0];
    int eCap = min(rp[n0 + 32], eBase + CAP);
    for (int i = eBase + t; i < eCap; i += 256)
        lcv[i - eBase] = make_int2(cols[i], __float_as_int(vals[i]));
    __syncthreads();

    int node = n0 + (t >> 3);
    unsigned tOff = (unsigned)(s * 128 + (t & 7) * 16);   // byte offset within row
    const char* sb = (const char*)src;                    // uniform SGPR base
    int e0 = rp[node], e1 = rp[node + 1];
    int le = e0 - eBase;
    int lEnd = min(e1, eCap) - eBase;
    float2v ac0 = {0,0}, ac1 = {0,0}, ac2 = {0,0}, ac3 = {0,0};

    uint4 qA0, qA1, qA2, qA3, qB0, qB1, qB2, qB3;
    int vA0, vA1, vA2, vA3, vB0, vB1, vB2, vB3;
    int e = le;
    if (e + 4 <= lEnd) {
        LD4(qA0, qA1, qA2, qA3, vA0, vA1, vA2, vA3, e);
        e += 4;
        // invariant at loop top: group A loaded for [e-4, e), not yet consumed
        while (e + 4 <= lEnd) {
            LD4(qB0, qB1, qB2, qB3, vB0, vB1, vB2, vB3, e);   // 8 loads in flight
            ACC4(qA0, qA1, qA2, qA3, vA0, vA1, vA2, vA3);
            e += 4;
            if (e + 4 <= lEnd) {
                LD4(qA0, qA1, qA2, qA3, vA0, vA1, vA2, vA3, e);
                ACC4(qB0, qB1, qB2, qB3, vB0, vB1, vB2, vB3);
                e += 4;
            } else {
                ACC4(qB0, qB1, qB2, qB3, vB0, vB1, vB2, vB3);
                goto pipe_done;
            }
        }
        ACC4(qA0, qA1, qA2, qA3, vA0, vA1, vA2, vA3);
    pipe_done: ;
    }
    for (; e < lEnd; ++e) {
        int2 cv = lcv[e];
        uint4 q = *(const uint4*)(sb + (size_t)(((unsigned)cv.x << 11) + tOff));
        accum(q, cv.y, ac0, ac1, ac2, ac3);
    }
    for (int a = e + eBase; a < e1; ++a) {   // overflow fallback (statistically never)
        int c = cols[a];
        uint4 q = *(const uint4*)(sb + (size_t)(((unsigned)c << 11) + tOff));
        accum(q, __float_as_int(vals[a]), ac0, ac1, ac2, ac3);
    }
    uint4 o;
    o.x = pack2(ac0[0], ac0[1]); o.y = pack2(ac1[0], ac1[1]);
    o.z = pack2(ac2[0], ac2[1]); o.w = pack2(ac3[0], ac3[1]);
    *(uint4*)((char*)dst + (size_t)node * 2048 + tOff) = o;
}

// fallback (no ws room for xb): gather fp32 inputs directly, emit bf16 y1
__global__ __launch_bounds__(256, 8) void spmm1_f32_k(
    const float* __restrict__ inputs, const int* __restrict__ cols,
    const float* __restrict__ vals, const int* __restrict__ rp,
    unsigned* __restrict__ y1) {
    __shared__ int2 lcv[CAP];
    int s = blockIdx.y, t = threadIdx.x;
    int n0 = blockIdx.x * 32;
    int eBase = rp[n0];
    int eCap = min(rp[n0 + 32], eBase + CAP);
    for (int i = eBase + t; i < eCap; i += 256)
        lcv[i - eBase] = make_int2(cols[i], __float_as_int(vals[i]));
    __syncthreads();

    int node = n0 + (t >> 3);
    const float* sp = inputs + (size_t)(s >> 1) * NN * 64 + (s & 1) * 32 + (t & 7) * 4;
    int e0 = rp[node], e1 = rp[node + 1];
    int eL = min(e1, eCap);
    float4 acc = make_float4(0.f, 0.f, 0.f, 0.f);
    #pragma unroll 2
    for (int e = e0; e < eL; ++e) {
        int2 cv = lcv[e - eBase];
        float v = __int_as_float(cv.y);
        float4 xv = *(const float4*)(sp + (size_t)cv.x * 64);
        acc.x += v * xv.x; acc.y += v * xv.y; acc.z += v * xv.z; acc.w += v * xv.w;
    }
    for (int e = eL; e < e1; ++e) {
        int c = cols[e]; float v = vals[e];
        float4 xv = *(const float4*)(sp + (size_t)c * 64);
        acc.x += v * xv.x; acc.y += v * xv.y; acc.z += v * xv.z; acc.w += v * xv.w;
    }
    uint2 o; o.x = pack2(acc.x, acc.y); o.y = pack2(acc.z, acc.w);
    *(uint2*)(y1 + (size_t)node * 512 + (s >> 1) * 32 + (s & 1) * 16 + (t & 7) * 2) = o;
}

// MFMA GEMM: out[b*NN+n][o] = [x0|y1|y2](bf16) @ Wt + bias, fp32 out.
// block = 64 nodes x 64 out x 2 b-iters; 4 waves, each 16n x 64o, K=192.
__global__ __launch_bounds__(256) void gemm_k(
    const float* __restrict__ inputs, const unsigned* __restrict__ xb,
    const unsigned* __restrict__ y1, const unsigned* __restrict__ y2,
    const unsigned short* __restrict__ wt, const float* __restrict__ bias,
    float* __restrict__ out) {
    __shared__ unsigned short wl[64 * WTP];   // 25.6 KB
    int t = threadIdx.x;
    for (int i = t; i < 1600; i += 256)
        ((uint4*)wl)[i] = ((const uint4*)wt)[i];
    __syncthreads();

    int w = t >> 6, l = t & 63;
    int lr = l & 15, lq = l >> 4;
    int n0 = blockIdx.x * 64 + w * 16;
    int nA = min(n0 + lr, NN - 1);   // clamped A-row (tail block)
    float bv0 = bias[lr], bv1 = bias[16 + lr], bv2 = bias[32 + lr], bv3 = bias[48 + lr];

    #pragma unroll
    for (int bb = 0; bb < 2; ++bb) {
        int b = blockIdx.y * 2 + bb;
        const unsigned* p1 = y1 + (size_t)nA * 512 + b * 32 + lq * 4;
        const unsigned* p2 = y2 + (size_t)nA * 512 + b * 32 + lq * 4;

        short8 a[6];
        if (xb) {
            const unsigned* p0 = xb + (size_t)nA * 512 + b * 32 + lq * 4;
            a[0] = *(const short8*)(p0);
            a[1] = *(const short8*)(p0 + 16);
        } else {
            const float* px = inputs + ((size_t)b * NN + nA) * 64 + lq * 8;
            float4 u0 = *(const float4*)(px);
            float4 u1 = *(const float4*)(px + 4);
            float4 u2 = *(const float4*)(px + 32);
            float4 u3 = *(const float4*)(px + 36);
            short8 t0, t1;
            t0[0] = (short)bf16rn(u0.x); t0[1] = (short)bf16rn(u0.y);
            t0[2] = (short)bf16rn(u0.z); t0[3] = (short)bf16rn(u0.w);
            t0[4] = (short)bf16rn(u1.x); t0[5] = (short)bf16rn(u1.y);
            t0[6] = (short)bf16rn(u1.z); t0[7] = (short)bf16rn(u1.w);
            t1[0] = (short)bf16rn(u2.x); t1[1] = (short)bf16rn(u2.y);
            t1[2] = (short)bf16rn(u2.z); t1[3] = (short)bf16rn(u2.w);
            t1[4] = (short)bf16rn(u3.x); t1[5] = (short)bf16rn(u3.y);
            t1[6] = (short)bf16rn(u3.z); t1[7] = (short)bf16rn(u3.w);
            a[0] = t0; a[1] = t1;
        }
        a[2] = *(const short8*)(p1);
        a[3] = *(const short8*)(p1 + 16);
        a[4] = *(const short8*)(p2);
        a[5] = *(const short8*)(p2 + 16);

        float4v acc0 = {0,0,0,0}, acc1 = {0,0,0,0}, acc2 = {0,0,0,0}, acc3 = {0,0,0,0};
        #pragma unroll
        for (int ks = 0; ks < 6; ++ks) {
            int kk = ks * 32 + lq * 8;
            short8 b0 = *(const short8*)&wl[(lr +  0) * WTP + kk];
            short8 b1 = *(const short8*)&wl[(lr + 16) * WTP + kk];
            short8 b2 = *(const short8*)&wl[(lr + 32) * WTP + kk];
            short8 b3 = *(const short8*)&wl[(lr + 48) * WTP + kk];
            acc0 = __builtin_amdgcn_mfma_f32_16x16x32_bf16(a[ks], b0, acc0, 0, 0, 0);
            acc1 = __builtin_amdgcn_mfma_f32_16x16x32_bf16(a[ks], b1, acc1, 0, 0, 0);
            acc2 = __builtin_amdgcn_mfma_f32_16x16x32_bf16(a[ks], b2, acc2, 0, 0, 0);
            acc3 = __builtin_amdgcn_mfma_f32_16x16x32_bf16(a[ks], b3, acc3, 0, 0, 0);
        }
        #pragma unroll
        for (int r = 0; r < 4; ++r) {
            int n = n0 + lq * 4 + r;
            if (n < NN) {
                float* po = out + ((size_t)b * NN + n) * 64;
                po[lr]      = acc0[r] + bv0;
                po[16 + lr] = acc1[r] + bv1;
                po[32 + lr] = acc2[r] + bv2;
                po[48 + lr] = acc3[r] + bv3;
            }
        }
    }
}

extern "C" void kernel_launch(void* const* d_in, const int* in_sizes, int n_in,
                              void* d_out, int out_size, void* d_ws, size_t ws_size,
                              hipStream_t stream) {
    const float* inputs  = (const float*)d_in[0];
    const int*   sp_rows = (const int*)d_in[1];
    const int*   sp_cols = (const int*)d_in[2];
    const float* sp_vals = (const float*)d_in[3];
    const float* weight  = (const float*)d_in[4];
    const float* biases  = (const float*)d_in[5];
    float* out = (float*)d_out;

    const size_t ybytes = (size_t)NN * 512 * 4;   // 40.96 MB per bf16 matrix
    char* base = (char*)d_ws;
    unsigned* y1 = (unsigned*)base;
    unsigned* y2 = (unsigned*)(base + ybytes);
    size_t off = 2 * ybytes;
    const size_t tail = (((size_t)(NN + 1) * 4 + 15) & ~(size_t)15) + 64 * WTP * 2 + 64;
    bool useXb = ws_size >= 3 * ybytes + tail;
    unsigned* xb = nullptr;
    if (useXb) { xb = (unsigned*)(base + off); off += ybytes; }
    int* rp = (int*)(base + off);
    off += ((size_t)(NN + 1) * 4 + 15) & ~(size_t)15;
    unsigned short* wt = (unsigned short*)(base + off);

    build_rowptr_k<<<79, 256, 0, stream>>>(sp_rows, rp);
    wtprep_k<<<48, 256, 0, stream>>>(weight, wt);
    if (useXb) {
        castxb_k<<<NN, 256, 0, stream>>>(inputs, xb);
        spmm_bf16_k<<<10000, 256, 0, stream>>>(xb, sp_cols, sp_vals, rp, y1);
    } else {
        spmm1_f32_k<<<dim3(625, 32), 256, 0, stream>>>(inputs, sp_cols, sp_vals, rp, y1);
    }
    spmm_bf16_k<<<10000, 256, 0, stream>>>(y1, sp_cols, sp_vals, rp, y2);
    gemm_k<<<dim3(313, 8), 256, 0, stream>>>(inputs, xb, y1, y2, wt, biases, out);
}

// Round 2
// 353.602 us; speedup vs baseline: 2.2289x; 2.2289x over previous
//
#include <hip/hip_runtime.h>

#define NN 20000   // nodes
#define EE 640000  // edges
#define CAP 2048   // LDS edge-cache (int2) = 16 KB -> no occupancy throttle
#define WTP 200    // padded k-stride of transposed weight (breaks bank conflict)

typedef __attribute__((ext_vector_type(8))) short short8;
typedef __attribute__((ext_vector_type(4))) float float4v;
typedef __attribute__((ext_vector_type(2))) float float2v;

__device__ __forceinline__ unsigned bf16rn(float x) {
    unsigned u = __float_as_uint(x);
    return (u + 0x7FFFu + ((u >> 16) & 1u)) >> 16;
}
__device__ __forceinline__ unsigned pack2(float a, float b) {
    return bf16rn(a) | (bf16rn(b) << 16);
}
__device__ __forceinline__ float bflo(unsigned u) { return __uint_as_float(u << 16); }
__device__ __forceinline__ float bfhi(unsigned u) { return __uint_as_float(u & 0xFFFF0000u); }

__global__ void build_rowptr_k(const int* __restrict__ rows, int* __restrict__ rp) {
    int r = blockIdx.x * blockDim.x + threadIdx.x;
    if (r > NN) return;
    int lo = 0, hi = EE;
    while (lo < hi) {
        int mid = (lo + hi) >> 1;
        if (rows[mid] < r) lo = mid + 1; else hi = mid;
    }
    rp[r] = lo;
}

// inputs[b][n][f] fp32 -> xb[n][b*64+f] bf16 (node-major, matches y1/y2)
__global__ __launch_bounds__(256) void castxb_k(const float* __restrict__ inp,
                                                unsigned* __restrict__ xb) {
    int n = blockIdx.x, t = threadIdx.x;
    int b = t >> 4, f4 = (t & 15) << 2;
    float4 v = *(const float4*)(inp + ((size_t)b * NN + n) * 64 + f4);
    uint2 o; o.x = pack2(v.x, v.y); o.y = pack2(v.z, v.w);
    *(uint2*)(xb + (size_t)n * 512 + b * 32 + (f4 >> 1)) = o;
}

// Wt[o][k'] bf16, k' = m*64+f, Chebyshev fold: m0: W0-W2, m1: W1, m2: 2*W2
__global__ void wtprep_k(const float* __restrict__ W, unsigned short* __restrict__ wt) {
    int i = blockIdx.x * 256 + threadIdx.x;
    if (i >= 64 * 192) return;
    int o = i / 192, kp = i - o * 192;
    int m = kp >> 6, f = kp & 63;
    float w = W[(f * 3 + m) * 64 + o];
    if (m == 0) w -= W[(f * 3 + 2) * 64 + o];
    else if (m == 2) w += w;
    wt[o * WTP + kp] = (unsigned short)bf16rn(w);
}

__device__ __forceinline__ void accum(const uint4& q, int vbits,
                                      float2v& ac0, float2v& ac1,
                                      float2v& ac2, float2v& ac3) {
    float v_ = __int_as_float(vbits);
    float2v vv = {v_, v_};
    float2v p0 = {bflo(q.x), bfhi(q.x)};
    float2v p1 = {bflo(q.y), bfhi(q.y)};
    float2v p2 = {bflo(q.z), bfhi(q.z)};
    float2v p3 = {bflo(q.w), bfhi(q.w)};
    ac0 = __builtin_elementwise_fma(vv, p0, ac0);
    ac1 = __builtin_elementwise_fma(vv, p1, ac1);
    ac2 = __builtin_elementwise_fma(vv, p2, ac2);
    ac3 = __builtin_elementwise_fma(vv, p3, ac3);
}

// dst[n][c] = sum_e v * src[col][c], bf16 in/out.
// 1D grid of 10000 blocks, XCD-pinned slices: slice = (bid&7) + 8*((bid>>3)/625)
// so each XCD's 4MB L2 holds exactly one 2.56MB channel-slice at a time.
// Round-0 proven loop structure (4-deep, straight-line, VGPR=28, no spill);
// addressing is SGPR-base + 32-bit voffset (saddr form), LDS indices
// pre-subtracted by eBase. Do NOT deepen the pipeline here: 8 live uint4
// groups caused scratch spills (round-1: WRITE_SIZE 40->825 MB, L2 slice
// evicted, 3.6x regression).
__global__ __launch_bounds__(256, 8) void spmm_bf16_k(
    const unsigned* __restrict__ src, const int* __restrict__ cols,
    const float* __restrict__ vals, const int* __restrict__ rp,
    unsigned* __restrict__ dst) {
    __shared__ int2 lcv[CAP];
    int bid = blockIdx.x;
    int xcd = bid & 7, j = bid >> 3;
    int chunk = j % 625;
    int s = xcd + ((j / 625) << 3);
    int t = threadIdx.x;
    int n0 = chunk * 32;
    int eBase = rp[n0];
    int eCap = min(rp[n0 + 32], eBase + CAP);
    for (int i = eBase + t; i < eCap; i += 256)
        lcv[i - eBase] = make_int2(cols[i], __float_as_int(vals[i]));
    __syncthreads();

    int node = n0 + (t >> 3);
    unsigned tOff = (unsigned)(s * 128 + (t & 7) * 16);   // byte offset within row
    const char* sb = (const char*)src;                    // uniform SGPR base
    int e0 = rp[node], e1 = rp[node + 1];
    int eL = min(e1, eCap);
    int le = e0 - eBase, lEnd = eL - eBase;
    float2v ac0 = {0,0}, ac1 = {0,0}, ac2 = {0,0}, ac3 = {0,0};

    int e = le;
    // 4-deep pipelined main loop: 4 independent gathers in flight per wave
    for (; e + 4 <= lEnd; e += 4) {
        int2 c0 = lcv[e],     c1 = lcv[e + 1];
        int2 c2 = lcv[e + 2], c3 = lcv[e + 3];
        uint4 q0 = *(const uint4*)(sb + (((unsigned)c0.x << 11) + tOff));
        uint4 q1 = *(const uint4*)(sb + (((unsigned)c1.x << 11) + tOff));
        uint4 q2 = *(const uint4*)(sb + (((unsigned)c2.x << 11) + tOff));
        uint4 q3 = *(const uint4*)(sb + (((unsigned)c3.x << 11) + tOff));
        accum(q0, c0.y, ac0, ac1, ac2, ac3);
        accum(q1, c1.y, ac0, ac1, ac2, ac3);
        accum(q2, c2.y, ac0, ac1, ac2, ac3);
        accum(q3, c3.y, ac0, ac1, ac2, ac3);
    }
    for (; e < lEnd; ++e) {
        int2 cv = lcv[e];
        uint4 q = *(const uint4*)(sb + (((unsigned)cv.x << 11) + tOff));
        accum(q, cv.y, ac0, ac1, ac2, ac3);
    }
    for (int a = lEnd + eBase; a < e1; ++a) {   // overflow fallback (statistically never)
        int c = cols[a];
        uint4 q = *(const uint4*)(sb + (((unsigned)c << 11) + tOff));
        accum(q, __float_as_int(vals[a]), ac0, ac1, ac2, ac3);
    }
    uint4 o;
    o.x = pack2(ac0[0], ac0[1]); o.y = pack2(ac1[0], ac1[1]);
    o.z = pack2(ac2[0], ac2[1]); o.w = pack2(ac3[0], ac3[1]);
    *(uint4*)((char*)dst + (size_t)node * 2048 + tOff) = o;
}

// fallback (no ws room for xb): gather fp32 inputs directly, emit bf16 y1
__global__ __launch_bounds__(256, 8) void spmm1_f32_k(
    const float* __restrict__ inputs, const int* __restrict__ cols,
    const float* __restrict__ vals, const int* __restrict__ rp,
    unsigned* __restrict__ y1) {
    __shared__ int2 lcv[CAP];
    int s = blockIdx.y, t = threadIdx.x;
    int n0 = blockIdx.x * 32;
    int eBase = rp[n0];
    int eCap = min(rp[n0 + 32], eBase + CAP);
    for (int i = eBase + t; i < eCap; i += 256)
        lcv[i - eBase] = make_int2(cols[i], __float_as_int(vals[i]));
    __syncthreads();

    int node = n0 + (t >> 3);
    const float* sp = inputs + (size_t)(s >> 1) * NN * 64 + (s & 1) * 32 + (t & 7) * 4;
    int e0 = rp[node], e1 = rp[node + 1];
    int eL = min(e1, eCap);
    float4 acc = make_float4(0.f, 0.f, 0.f, 0.f);
    #pragma unroll 2
    for (int e = e0; e < eL; ++e) {
        int2 cv = lcv[e - eBase];
        float v = __int_as_float(cv.y);
        float4 xv = *(const float4*)(sp + (size_t)cv.x * 64);
        acc.x += v * xv.x; acc.y += v * xv.y; acc.z += v * xv.z; acc.w += v * xv.w;
    }
    for (int e = eL; e < e1; ++e) {
        int c = cols[e]; float v = vals[e];
        float4 xv = *(const float4*)(sp + (size_t)c * 64);
        acc.x += v * xv.x; acc.y += v * xv.y; acc.z += v * xv.z; acc.w += v * xv.w;
    }
    uint2 o; o.x = pack2(acc.x, acc.y); o.y = pack2(acc.z, acc.w);
    *(uint2*)(y1 + (size_t)node * 512 + (s >> 1) * 32 + (s & 1) * 16 + (t & 7) * 2) = o;
}

// MFMA GEMM: out[b*NN+n][o] = [x0|y1|y2](bf16) @ Wt + bias, fp32 out.
// block = 64 nodes x 64 out x 2 b-iters; 4 waves, each 16n x 64o, K=192.
__global__ __launch_bounds__(256) void gemm_k(
    const float* __restrict__ inputs, const unsigned* __restrict__ xb,
    const unsigned* __restrict__ y1, const unsigned* __restrict__ y2,
    const unsigned short* __restrict__ wt, const float* __restrict__ bias,
    float* __restrict__ out) {
    __shared__ unsigned short wl[64 * WTP];   // 25.6 KB
    int t = threadIdx.x;
    for (int i = t; i < 1600; i += 256)
        ((uint4*)wl)[i] = ((const uint4*)wt)[i];
    __syncthreads();

    int w = t >> 6, l = t & 63;
    int lr = l & 15, lq = l >> 4;
    int n0 = blockIdx.x * 64 + w * 16;
    int nA = min(n0 + lr, NN - 1);   // clamped A-row (tail block)
    float bv0 = bias[lr], bv1 = bias[16 + lr], bv2 = bias[32 + lr], bv3 = bias[48 + lr];

    #pragma unroll
    for (int bb = 0; bb < 2; ++bb) {
        int b = blockIdx.y * 2 + bb;
        const unsigned* p1 = y1 + (size_t)nA * 512 + b * 32 + lq * 4;
        const unsigned* p2 = y2 + (size_t)nA * 512 + b * 32 + lq * 4;

        short8 a[6];
        if (xb) {
            const unsigned* p0 = xb + (size_t)nA * 512 + b * 32 + lq * 4;
            a[0] = *(const short8*)(p0);
            a[1] = *(const short8*)(p0 + 16);
        } else {
            const float* px = inputs + ((size_t)b * NN + nA) * 64 + lq * 8;
            float4 u0 = *(const float4*)(px);
            float4 u1 = *(const float4*)(px + 4);
            float4 u2 = *(const float4*)(px + 32);
            float4 u3 = *(const float4*)(px + 36);
            short8 t0, t1;
            t0[0] = (short)bf16rn(u0.x); t0[1] = (short)bf16rn(u0.y);
            t0[2] = (short)bf16rn(u0.z); t0[3] = (short)bf16rn(u0.w);
            t0[4] = (short)bf16rn(u1.x); t0[5] = (short)bf16rn(u1.y);
            t0[6] = (short)bf16rn(u1.z); t0[7] = (short)bf16rn(u1.w);
            t1[0] = (short)bf16rn(u2.x); t1[1] = (short)bf16rn(u2.y);
            t1[2] = (short)bf16rn(u2.z); t1[3] = (short)bf16rn(u2.w);
            t1[4] = (short)bf16rn(u3.x); t1[5] = (short)bf16rn(u3.y);
            t1[6] = (short)bf16rn(u3.z); t1[7] = (short)bf16rn(u3.w);
            a[0] = t0; a[1] = t1;
        }
        a[2] = *(const short8*)(p1);
        a[3] = *(const short8*)(p1 + 16);
        a[4] = *(const short8*)(p2);
        a[5] = *(const short8*)(p2 + 16);

        float4v acc0 = {0,0,0,0}, acc1 = {0,0,0,0}, acc2 = {0,0,0,0}, acc3 = {0,0,0,0};
        #pragma unroll
        for (int ks = 0; ks < 6; ++ks) {
            int kk = ks * 32 + lq * 8;
            short8 b0 = *(const short8*)&wl[(lr +  0) * WTP + kk];
            short8 b1 = *(const short8*)&wl[(lr + 16) * WTP + kk];
            short8 b2 = *(const short8*)&wl[(lr + 32) * WTP + kk];
            short8 b3 = *(const short8*)&wl[(lr + 48) * WTP + kk];
            acc0 = __builtin_amdgcn_mfma_f32_16x16x32_bf16(a[ks], b0, acc0, 0, 0, 0);
            acc1 = __builtin_amdgcn_mfma_f32_16x16x32_bf16(a[ks], b1, acc1, 0, 0, 0);
            acc2 = __builtin_amdgcn_mfma_f32_16x16x32_bf16(a[ks], b2, acc2, 0, 0, 0);
            acc3 = __builtin_amdgcn_mfma_f32_16x16x32_bf16(a[ks], b3, acc3, 0, 0, 0);
        }
        #pragma unroll
        for (int r = 0; r < 4; ++r) {
            int n = n0 + lq * 4 + r;
            if (n < NN) {
                float* po = out + ((size_t)b * NN + n) * 64;
                po[lr]      = acc0[r] + bv0;
                po[16 + lr] = acc1[r] + bv1;
                po[32 + lr] = acc2[r] + bv2;
                po[48 + lr] = acc3[r] + bv3;
            }
        }
    }
}

extern "C" void kernel_launch(void* const* d_in, const int* in_sizes, int n_in,
                              void* d_out, int out_size, void* d_ws, size_t ws_size,
                              hipStream_t stream) {
    const float* inputs  = (const float*)d_in[0];
    const int*   sp_rows = (const int*)d_in[1];
    const int*   sp_cols = (const int*)d_in[2];
    const float* sp_vals = (const float*)d_in[3];
    const float* weight  = (const float*)d_in[4];
    const float* biases  = (const float*)d_in[5];
    float* out = (float*)d_out;

    const size_t ybytes = (size_t)NN * 512 * 4;   // 40.96 MB per bf16 matrix
    char* base = (char*)d_ws;
    unsigned* y1 = (unsigned*)base;
    unsigned* y2 = (unsigned*)(base + ybytes);
    size_t off = 2 * ybytes;
    const size_t tail = (((size_t)(NN + 1) * 4 + 15) & ~(size_t)15) + 64 * WTP * 2 + 64;
    bool useXb = ws_size >= 3 * ybytes + tail;
    unsigned* xb = nullptr;
    if (useXb) { xb = (unsigned*)(base + off); off += ybytes; }
    int* rp = (int*)(base + off);
    off += ((size_t)(NN + 1) * 4 + 15) & ~(size_t)15;
    unsigned short* wt = (unsigned short*)(base + off);

    build_rowptr_k<<<79, 256, 0, stream>>>(sp_rows, rp);
    wtprep_k<<<48, 256, 0, stream>>>(weight, wt);
    if (useXb) {
        castxb_k<<<NN, 256, 0, stream>>>(inputs, xb);
        spmm_bf16_k<<<10000, 256, 0, stream>>>(xb, sp_cols, sp_vals, rp, y1);
    } else {
        spmm1_f32_k<<<dim3(625, 32), 256, 0, stream>>>(inputs, sp_cols, sp_vals, rp, y1);
    }
    spmm_bf16_k<<<10000, 256, 0, stream>>>(y1, sp_cols, sp_vals, rp, y2);
    gemm_k<<<dim3(313, 8), 256, 0, stream>>>(inputs, xb, y1, y2, wt, biases, out);
}

// Round 3
// 352.670 us; speedup vs baseline: 2.2348x; 1.0026x over previous
//
#include <hip/hip_runtime.h>

#define NN 20000   // nodes
#define EE 640000  // edges
#define CAP 2048   // LDS edge-cache (int2) = 16 KB -> no occupancy throttle
#define WTP 200    // padded k-stride of transposed weight (breaks bank conflict)

typedef __attribute__((ext_vector_type(8))) short short8;
typedef __attribute__((ext_vector_type(4))) float float4v;
typedef __attribute__((ext_vector_type(2))) float float2v;

__device__ __forceinline__ unsigned bf16rn(float x) {
    unsigned u = __float_as_uint(x);
    return (u + 0x7FFFu + ((u >> 16) & 1u)) >> 16;
}
__device__ __forceinline__ unsigned pack2(float a, float b) {
    return bf16rn(a) | (bf16rn(b) << 16);
}
__device__ __forceinline__ float bflo(unsigned u) { return __uint_as_float(u << 16); }
__device__ __forceinline__ float bfhi(unsigned u) { return __uint_as_float(u & 0xFFFF0000u); }

__global__ void build_rowptr_k(const int* __restrict__ rows, int* __restrict__ rp) {
    int r = blockIdx.x * blockDim.x + threadIdx.x;
    if (r > NN) return;
    int lo = 0, hi = EE;
    while (lo < hi) {
        int mid = (lo + hi) >> 1;
        if (rows[mid] < r) lo = mid + 1; else hi = mid;
    }
    rp[r] = lo;
}

// inputs[b][n][f] fp32 -> xb[n][b*64+f] bf16 (node-major, matches y1/y2)
__global__ __launch_bounds__(256) void castxb_k(const float* __restrict__ inp,
                                                unsigned* __restrict__ xb) {
    int n = blockIdx.x, t = threadIdx.x;
    int b = t >> 4, f4 = (t & 15) << 2;
    float4 v = *(const float4*)(inp + ((size_t)b * NN + n) * 64 + f4);
    uint2 o; o.x = pack2(v.x, v.y); o.y = pack2(v.z, v.w);
    *(uint2*)(xb + (size_t)n * 512 + b * 32 + (f4 >> 1)) = o;
}

// Wt[o][k'] bf16, k' = m*64+f, Chebyshev fold: m0: W0-W2, m1: W1, m2: 2*W2
__global__ void wtprep_k(const float* __restrict__ W, unsigned short* __restrict__ wt) {
    int i = blockIdx.x * 256 + threadIdx.x;
    if (i >= 64 * 192) return;
    int o = i / 192, kp = i - o * 192;
    int m = kp >> 6, f = kp & 63;
    float w = W[(f * 3 + m) * 64 + o];
    if (m == 0) w -= W[(f * 3 + 2) * 64 + o];
    else if (m == 2) w += w;
    wt[o * WTP + kp] = (unsigned short)bf16rn(w);
}

__device__ __forceinline__ void accum(const uint4& q, int vbits,
                                      float2v& ac0, float2v& ac1,
                                      float2v& ac2, float2v& ac3) {
    float v_ = __int_as_float(vbits);
    float2v vv = {v_, v_};
    float2v p0 = {bflo(q.x), bfhi(q.x)};
    float2v p1 = {bflo(q.y), bfhi(q.y)};
    float2v p2 = {bflo(q.z), bfhi(q.z)};
    float2v p3 = {bflo(q.w), bfhi(q.w)};
    ac0 = __builtin_elementwise_fma(vv, p0, ac0);
    ac1 = __builtin_elementwise_fma(vv, p1, ac1);
    ac2 = __builtin_elementwise_fma(vv, p2, ac2);
    ac3 = __builtin_elementwise_fma(vv, p3, ac3);
}

// dst[n][c] = sum_e v * src[col][c], bf16 in/out.
// 1D grid of 10000 blocks, XCD-pinned slices: slice = (bid&7) + 8*((bid>>3)/625)
// so each XCD's 4MB L2 holds exactly one 2.56MB channel-slice at a time.
// Latency-bound (round-2: VALU diet 67->58% busy, dur flat): the lever is
// in-flight gathers. 8-deep STRAIGHT-LINE unroll (no goto/ping-pong — that
// CFG caused scratch spills in round-1: WRITE 40->825 MB, 3.6x regression).
// launch_bounds(256,6): VGPR cap 85 so the ~62 live regs cannot spill;
// occupancy cap 24 waves/CU >= the ~21 achieved before.
__global__ __launch_bounds__(256, 6) void spmm_bf16_k(
    const unsigned* __restrict__ src, const int* __restrict__ cols,
    const float* __restrict__ vals, const int* __restrict__ rp,
    unsigned* __restrict__ dst) {
    __shared__ int2 lcv[CAP];
    int bid = blockIdx.x;
    int xcd = bid & 7, j = bid >> 3;
    int chunk = j % 625;
    int s = xcd + ((j / 625) << 3);
    int t = threadIdx.x;
    int n0 = chunk * 32;
    int eBase = rp[n0];
    int eCap = min(rp[n0 + 32], eBase + CAP);
    for (int i = eBase + t; i < eCap; i += 256)
        lcv[i - eBase] = make_int2(cols[i], __float_as_int(vals[i]));
    __syncthreads();

    int node = n0 + (t >> 3);
    unsigned tOff = (unsigned)(s * 128 + (t & 7) * 16);   // byte offset within row
    const char* sb = (const char*)src;                    // uniform SGPR base
    int e0 = rp[node], e1 = rp[node + 1];
    int eL = min(e1, eCap);
    int le = e0 - eBase, lEnd = eL - eBase;
    float2v ac0 = {0,0}, ac1 = {0,0}, ac2 = {0,0}, ac3 = {0,0};

    int e = le;
    // 8 independent gathers in flight per wave, single straight-line body
    for (; e + 8 <= lEnd; e += 8) {
        int2 c0 = lcv[e],     c1 = lcv[e + 1];
        int2 c2 = lcv[e + 2], c3 = lcv[e + 3];
        int2 c4 = lcv[e + 4], c5 = lcv[e + 5];
        int2 c6 = lcv[e + 6], c7 = lcv[e + 7];
        uint4 q0 = *(const uint4*)(sb + (((unsigned)c0.x << 11) + tOff));
        uint4 q1 = *(const uint4*)(sb + (((unsigned)c1.x << 11) + tOff));
        uint4 q2 = *(const uint4*)(sb + (((unsigned)c2.x << 11) + tOff));
        uint4 q3 = *(const uint4*)(sb + (((unsigned)c3.x << 11) + tOff));
        uint4 q4 = *(const uint4*)(sb + (((unsigned)c4.x << 11) + tOff));
        uint4 q5 = *(const uint4*)(sb + (((unsigned)c5.x << 11) + tOff));
        uint4 q6 = *(const uint4*)(sb + (((unsigned)c6.x << 11) + tOff));
        uint4 q7 = *(const uint4*)(sb + (((unsigned)c7.x << 11) + tOff));
        accum(q0, c0.y, ac0, ac1, ac2, ac3);
        accum(q1, c1.y, ac0, ac1, ac2, ac3);
        accum(q2, c2.y, ac0, ac1, ac2, ac3);
        accum(q3, c3.y, ac0, ac1, ac2, ac3);
        accum(q4, c4.y, ac0, ac1, ac2, ac3);
        accum(q5, c5.y, ac0, ac1, ac2, ac3);
        accum(q6, c6.y, ac0, ac1, ac2, ac3);
        accum(q7, c7.y, ac0, ac1, ac2, ac3);
    }
    for (; e + 4 <= lEnd; e += 4) {
        int2 c0 = lcv[e],     c1 = lcv[e + 1];
        int2 c2 = lcv[e + 2], c3 = lcv[e + 3];
        uint4 q0 = *(const uint4*)(sb + (((unsigned)c0.x << 11) + tOff));
        uint4 q1 = *(const uint4*)(sb + (((unsigned)c1.x << 11) + tOff));
        uint4 q2 = *(const uint4*)(sb + (((unsigned)c2.x << 11) + tOff));
        uint4 q3 = *(const uint4*)(sb + (((unsigned)c3.x << 11) + tOff));
        accum(q0, c0.y, ac0, ac1, ac2, ac3);
        accum(q1, c1.y, ac0, ac1, ac2, ac3);
        accum(q2, c2.y, ac0, ac1, ac2, ac3);
        accum(q3, c3.y, ac0, ac1, ac2, ac3);
    }
    for (; e < lEnd; ++e) {
        int2 cv = lcv[e];
        uint4 q = *(const uint4*)(sb + (((unsigned)cv.x << 11) + tOff));
        accum(q, cv.y, ac0, ac1, ac2, ac3);
    }
    for (int a = lEnd + eBase; a < e1; ++a) {   // overflow fallback (statistically never)
        int c = cols[a];
        uint4 q = *(const uint4*)(sb + (((unsigned)c << 11) + tOff));
        accum(q, __float_as_int(vals[a]), ac0, ac1, ac2, ac3);
    }
    uint4 o;
    o.x = pack2(ac0[0], ac0[1]); o.y = pack2(ac1[0], ac1[1]);
    o.z = pack2(ac2[0], ac2[1]); o.w = pack2(ac3[0], ac3[1]);
    *(uint4*)((char*)dst + (size_t)node * 2048 + tOff) = o;
}

// fallback (no ws room for xb): gather fp32 inputs directly, emit bf16 y1
__global__ __launch_bounds__(256, 8) void spmm1_f32_k(
    const float* __restrict__ inputs, const int* __restrict__ cols,
    const float* __restrict__ vals, const int* __restrict__ rp,
    unsigned* __restrict__ y1) {
    __shared__ int2 lcv[CAP];
    int s = blockIdx.y, t = threadIdx.x;
    int n0 = blockIdx.x * 32;
    int eBase = rp[n0];
    int eCap = min(rp[n0 + 32], eBase + CAP);
    for (int i = eBase + t; i < eCap; i += 256)
        lcv[i - eBase] = make_int2(cols[i], __float_as_int(vals[i]));
    __syncthreads();

    int node = n0 + (t >> 3);
    const float* sp = inputs + (size_t)(s >> 1) * NN * 64 + (s & 1) * 32 + (t & 7) * 4;
    int e0 = rp[node], e1 = rp[node + 1];
    int eL = min(e1, eCap);
    float4 acc = make_float4(0.f, 0.f, 0.f, 0.f);
    #pragma unroll 2
    for (int e = e0; e < eL; ++e) {
        int2 cv = lcv[e - eBase];
        float v = __int_as_float(cv.y);
        float4 xv = *(const float4*)(sp + (size_t)cv.x * 64);
        acc.x += v * xv.x; acc.y += v * xv.y; acc.z += v * xv.z; acc.w += v * xv.w;
    }
    for (int e = eL; e < e1; ++e) {
        int c = cols[e]; float v = vals[e];
        float4 xv = *(const float4*)(sp + (size_t)c * 64);
        acc.x += v * xv.x; acc.y += v * xv.y; acc.z += v * xv.z; acc.w += v * xv.w;
    }
    uint2 o; o.x = pack2(acc.x, acc.y); o.y = pack2(acc.z, acc.w);
    *(uint2*)(y1 + (size_t)node * 512 + (s >> 1) * 32 + (s & 1) * 16 + (t & 7) * 2) = o;
}

// MFMA GEMM: out[b*NN+n][o] = [x0|y1|y2](bf16) @ Wt + bias, fp32 out.
// block = 64 nodes x 64 out x 2 b-iters; 4 waves, each 16n x 64o, K=192.
__global__ __launch_bounds__(256) void gemm_k(
    const float* __restrict__ inputs, const unsigned* __restrict__ xb,
    const unsigned* __restrict__ y1, const unsigned* __restrict__ y2,
    const unsigned short* __restrict__ wt, const float* __restrict__ bias,
    float* __restrict__ out) {
    __shared__ unsigned short wl[64 * WTP];   // 25.6 KB
    int t = threadIdx.x;
    for (int i = t; i < 1600; i += 256)
        ((uint4*)wl)[i] = ((const uint4*)wt)[i];
    __syncthreads();

    int w = t >> 6, l = t & 63;
    int lr = l & 15, lq = l >> 4;
    int n0 = blockIdx.x * 64 + w * 16;
    int nA = min(n0 + lr, NN - 1);   // clamped A-row (tail block)
    float bv0 = bias[lr], bv1 = bias[16 + lr], bv2 = bias[32 + lr], bv3 = bias[48 + lr];

    #pragma unroll
    for (int bb = 0; bb < 2; ++bb) {
        int b = blockIdx.y * 2 + bb;
        const unsigned* p1 = y1 + (size_t)nA * 512 + b * 32 + lq * 4;
        const unsigned* p2 = y2 + (size_t)nA * 512 + b * 32 + lq * 4;

        short8 a[6];
        if (xb) {
            const unsigned* p0 = xb + (size_t)nA * 512 + b * 32 + lq * 4;
            a[0] = *(const short8*)(p0);
            a[1] = *(const short8*)(p0 + 16);
        } else {
            const float* px = inputs + ((size_t)b * NN + nA) * 64 + lq * 8;
            float4 u0 = *(const float4*)(px);
            float4 u1 = *(const float4*)(px + 4);
            float4 u2 = *(const float4*)(px + 32);
            float4 u3 = *(const float4*)(px + 36);
            short8 t0, t1;
            t0[0] = (short)bf16rn(u0.x); t0[1] = (short)bf16rn(u0.y);
            t0[2] = (short)bf16rn(u0.z); t0[3] = (short)bf16rn(u0.w);
            t0[4] = (short)bf16rn(u1.x); t0[5] = (short)bf16rn(u1.y);
            t0[6] = (short)bf16rn(u1.z); t0[7] = (short)bf16rn(u1.w);
            t1[0] = (short)bf16rn(u2.x); t1[1] = (short)bf16rn(u2.y);
            t1[2] = (short)bf16rn(u2.z); t1[3] = (short)bf16rn(u2.w);
            t1[4] = (short)bf16rn(u3.x); t1[5] = (short)bf16rn(u3.y);
            t1[6] = (short)bf16rn(u3.z); t1[7] = (short)bf16rn(u3.w);
            a[0] = t0; a[1] = t1;
        }
        a[2] = *(const short8*)(p1);
        a[3] = *(const short8*)(p1 + 16);
        a[4] = *(const short8*)(p2);
        a[5] = *(const short8*)(p2 + 16);

        float4v acc0 = {0,0,0,0}, acc1 = {0,0,0,0}, acc2 = {0,0,0,0}, acc3 = {0,0,0,0};
        #pragma unroll
        for (int ks = 0; ks < 6; ++ks) {
            int kk = ks * 32 + lq * 8;
            short8 b0 = *(const short8*)&wl[(lr +  0) * WTP + kk];
            short8 b1 = *(const short8*)&wl[(lr + 16) * WTP + kk];
            short8 b2 = *(const short8*)&wl[(lr + 32) * WTP + kk];
            short8 b3 = *(const short8*)&wl[(lr + 48) * WTP + kk];
            acc0 = __builtin_amdgcn_mfma_f32_16x16x32_bf16(a[ks], b0, acc0, 0, 0, 0);
            acc1 = __builtin_amdgcn_mfma_f32_16x16x32_bf16(a[ks], b1, acc1, 0, 0, 0);
            acc2 = __builtin_amdgcn_mfma_f32_16x16x32_bf16(a[ks], b2, acc2, 0, 0, 0);
            acc3 = __builtin_amdgcn_mfma_f32_16x16x32_bf16(a[ks], b3, acc3, 0, 0, 0);
        }
        #pragma unroll
        for (int r = 0; r < 4; ++r) {
            int n = n0 + lq * 4 + r;
            if (n < NN) {
                float* po = out + ((size_t)b * NN + n) * 64;
                po[lr]      = acc0[r] + bv0;
                po[16 + lr] = acc1[r] + bv1;
                po[32 + lr] = acc2[r] + bv2;
                po[48 + lr] = acc3[r] + bv3;
            }
        }
    }
}

extern "C" void kernel_launch(void* const* d_in, const int* in_sizes, int n_in,
                              void* d_out, int out_size, void* d_ws, size_t ws_size,
                              hipStream_t stream) {
    const float* inputs  = (const float*)d_in[0];
    const int*   sp_rows = (const int*)d_in[1];
    const int*   sp_cols = (const int*)d_in[2];
    const float* sp_vals = (const float*)d_in[3];
    const float* weight  = (const float*)d_in[4];
    const float* biases  = (const float*)d_in[5];
    float* out = (float*)d_out;

    const size_t ybytes = (size_t)NN * 512 * 4;   // 40.96 MB per bf16 matrix
    char* base = (char*)d_ws;
    unsigned* y1 = (unsigned*)base;
    unsigned* y2 = (unsigned*)(base + ybytes);
    size_t off = 2 * ybytes;
    const size_t tail = (((size_t)(NN + 1) * 4 + 15) & ~(size_t)15) + 64 * WTP * 2 + 64;
    bool useXb = ws_size >= 3 * ybytes + tail;
    unsigned* xb = nullptr;
    if (useXb) { xb = (unsigned*)(base + off); off += ybytes; }
    int* rp = (int*)(base + off);
    off += ((size_t)(NN + 1) * 4 + 15) & ~(size_t)15;
    unsigned short* wt = (unsigned short*)(base + off);

    build_rowptr_k<<<79, 256, 0, stream>>>(sp_rows, rp);
    wtprep_k<<<48, 256, 0, stream>>>(weight, wt);
    if (useXb) {
        castxb_k<<<NN, 256, 0, stream>>>(inputs, xb);
        spmm_bf16_k<<<10000, 256, 0, stream>>>(xb, sp_cols, sp_vals, rp, y1);
    } else {
        spmm1_f32_k<<<dim3(625, 32), 256, 0, stream>>>(inputs, sp_cols, sp_vals, rp, y1);
    }
    spmm_bf16_k<<<10000, 256, 0, stream>>>(y1, sp_cols, sp_vals, rp, y2);
    gemm_k<<<dim3(313, 8), 256, 0, stream>>>(inputs, xb, y1, y2, wt, biases, out);
}